// Round 6
// baseline (355.583 us; speedup 1.0000x reference)
//
#include <hip/hip_runtime.h>

typedef unsigned short u16;
typedef __attribute__((ext_vector_type(8))) short short8;
typedef __attribute__((ext_vector_type(4))) unsigned short ushort4v;
typedef __attribute__((ext_vector_type(4))) float float4v;

__device__ __forceinline__ float bf2f(u16 u) {
  union { unsigned int i; float f; } c; c.i = ((unsigned int)u) << 16; return c.f;
}
__device__ __forceinline__ u16 f2bf(float f) {
  union { float f; unsigned int i; } c; c.f = f;
  unsigned int u = c.i;
  return (u16)((u + 0x7fffu + ((u >> 16) & 1u)) >> 16);
}
// packed f32x2 -> bf16x2 (RNE), lo = bf16(a), hi = bf16(b)
__device__ __forceinline__ unsigned int cvt_pk_bf16(float a, float b) {
  unsigned int r;
  asm("v_cvt_pk_bf16_f32 %0, %1, %2" : "=v"(r) : "v"(a), "v"(b));
  return r;
}
// 0.5x(1+tanh(c(x+0.044715x^3))) == x / (1 + exp2(-(k1*x + k3*x^3)))
__device__ __forceinline__ float gelu_new(float x) {
  const float k1 = 2.30218776f;
  const float k3 = 0.10294233f;
  float x3 = x * x * x;
  float e = __builtin_amdgcn_exp2f(-(k1 * x + k3 * x3));
  return x / (1.0f + e);
}
__device__ __forceinline__ float ldres(const float* p) { return *p; }
__device__ __forceinline__ float ldres(const u16* p) { return bf2f(*p); }

__device__ __forceinline__ void gload_lds16(const u16* g, u16* l) {
  __builtin_amdgcn_global_load_lds(
      (const __attribute__((address_space(1))) unsigned int*)g,
      (__attribute__((address_space(3))) unsigned int*)l, 16, 0, 0);
}

// ---------------- prep kernels ----------------
__global__ void cvt_bf16_multi(const float* __restrict__ s0, const float* __restrict__ s1,
                               const float* __restrict__ s2, const float* __restrict__ s3,
                               const float* __restrict__ s4, u16* __restrict__ d0,
                               u16* __restrict__ d1, u16* __restrict__ d2,
                               u16* __restrict__ d3, u16* __restrict__ d4) {
  int bid = blockIdx.x;
  const float* src; u16* dst; int base;
  if (bid < 512)       { src = s0; dst = d0; base = 0; }
  else if (bid < 1024) { src = s1; dst = d1; base = 512; }
  else if (bid < 1536) { src = s2; dst = d2; base = 1024; }
  else if (bid < 3584) { src = s3; dst = d3; base = 1536; }
  else                 { src = s4; dst = d4; base = 3584; }
  int t = (bid - base) * 256 + threadIdx.x;
  float4v a = *(const float4v*)(src + (size_t)t * 8);
  float4v b = *(const float4v*)(src + (size_t)t * 8 + 4);
  short8 o;
#pragma unroll
  for (int j = 0; j < 4; ++j) o[j] = (short)f2bf(a[j]);
#pragma unroll
  for (int j = 0; j < 4; ++j) o[4 + j] = (short)f2bf(b[j]);
  *(short8*)(dst + (size_t)t * 8) = o;
}

// W_O [16,1024,64] f32 -> Wot[d, i*64+h] bf16
__global__ void prep_wo(const float* __restrict__ WO, u16* __restrict__ Wot) {
  int t = blockIdx.x * 256 + threadIdx.x;  // 0..131071
  int i = t >> 13;
  int d = (t >> 3) & 1023;
  int h0 = (t & 7) * 8;
  const float* src = WO + (size_t)i * 65536 + d * 64 + h0;
  float4v a = *(const float4v*)(src);
  float4v b = *(const float4v*)(src + 4);
  short8 o;
#pragma unroll
  for (int j = 0; j < 4; ++j) o[j] = (short)f2bf(a[j]);
#pragma unroll
  for (int j = 0; j < 4; ++j) o[4 + j] = (short)f2bf(b[j]);
  *(short8*)(Wot + (size_t)d * 1024 + i * 64 + h0) = o;
}

__global__ void prep_bqkv(const float* __restrict__ bQ, const float* __restrict__ bK,
                          const float* __restrict__ bV, float* __restrict__ bqkv) {
  int t = blockIdx.x * 256 + threadIdx.x;
  if (t < 3072)
    bqkv[t] = (t < 1024) ? bQ[t] : (t < 2048) ? bK[t - 1024] : bV[t - 2048];
}

// ---------------- layernorm (ln_pre): f32 in -> bf16 out ----------------
__global__ void ln_f32(const float* __restrict__ x, u16* __restrict__ y) {
  __shared__ float red1[4];
  __shared__ float red2[4];
  int token = blockIdx.x;
  int tid = threadIdx.x;
  int w = tid >> 6;
  const float* xr = x + (size_t)token * 1024;
  float4v v = *(const float4v*)(xr + tid * 4);
  float s = v[0] + v[1] + v[2] + v[3];
#pragma unroll
  for (int m = 32; m >= 1; m >>= 1) s += __shfl_xor(s, m);
  if ((tid & 63) == 0) red1[w] = s;
  __syncthreads();
  float mean = (red1[0] + red1[1] + red1[2] + red1[3]) * (1.0f / 1024.0f);
  float ss = 0.0f;
#pragma unroll
  for (int j = 0; j < 4; ++j) { v[j] -= mean; ss += v[j] * v[j]; }
#pragma unroll
  for (int m = 32; m >= 1; m >>= 1) ss += __shfl_xor(ss, m);
  if ((tid & 63) == 0) red2[w] = ss;
  __syncthreads();
  float ms = (red2[0] + red2[1] + red2[2] + red2[3]) * (1.0f / 1024.0f);
  float inv = 1.0f / sqrtf(ms + 1e-5f);
  ushort4v o;
#pragma unroll
  for (int j = 0; j < 4; ++j) o[j] = f2bf(v[j] * inv);
  *(ushort4v*)(y + (size_t)token * 1024 + tid * 4) = o;
}

// ---------------- GEMM: C[M,N] = A[M,K](bf16, stride lda) * Bw[N,K]^T ----------------
// (128x BN tile, 2-barrier structure; swizzled LDS; optional prefetch dbuf)
template <int BN, int BK, bool GELU, bool VSPLIT, bool DBUF, typename TO, typename TR>
__global__ __launch_bounds__(256) void gemm_bt(
    const u16* __restrict__ A, const u16* __restrict__ Bw,
    const float* __restrict__ bias, const TR* __restrict__ resid,
    TO* __restrict__ C, u16* __restrict__ vTout, int M, int N, int K,
    int lda, int ldc) {
  constexpr int BM = 128;
  constexpr int SEGS = BK / 8;           // 16B chunks per tile row
  constexpr int SMASK = SEGS - 1;
  constexpr int FI = 4, FJ = BN / 32;
  constexpr int CA = BM * SEGS / 256;    // chunks per thread (A tile)
  constexpr int CB = BN * SEGS / 256;
  constexpr int NB = DBUF ? 2 : 1;
  __shared__ __align__(16) u16 As[NB][BM * BK];
  __shared__ __align__(16) u16 Bs[NB][BN * BK];
  const int tid = threadIdx.x;
  const int w = tid >> 6, lane = tid & 63;
  const int quad = lane >> 4, l16 = lane & 15;
  const int m0 = blockIdx.x * BM, n0 = blockIdx.y * BN;
  const int wm = (w >> 1) * 64, wn = (w & 1) * (BN / 2);
  const int rmask = l16 & SMASK;  // == row & SMASK for all fragment rows
  float4v acc[FI][FJ] = {};

  auto stage = [&](int buf, int k0) {
#pragma unroll
    for (int t = 0; t < CA; ++t) {
      int chunk = (w * CA + t) * 64 + lane;
      int row = chunk / SEGS, seg = chunk % SEGS;
      int sseg = seg ^ (row & SMASK);
      gload_lds16(A + (size_t)(m0 + row) * lda + k0 + sseg * 8,
                  As[buf] + (w * CA + t) * 512);
    }
#pragma unroll
    for (int t = 0; t < CB; ++t) {
      int chunk = (w * CB + t) * 64 + lane;
      int row = chunk / SEGS, seg = chunk % SEGS;
      int sseg = seg ^ (row & SMASK);
      gload_lds16(Bw + (size_t)(n0 + row) * K + k0 + sseg * 8,
                  Bs[buf] + (w * CB + t) * 512);
    }
  };
  auto compute = [&](int buf) {
#pragma unroll
    for (int kk = 0; kk < BK; kk += 32) {
      short8 a[FI], b[FJ];
#pragma unroll
      for (int fi = 0; fi < FI; ++fi)
        a[fi] = *(const short8*)(As[buf] + (wm + fi * 16 + l16) * BK +
                                 ((((kk >> 3) + quad) ^ rmask) << 3));
#pragma unroll
      for (int fj = 0; fj < FJ; ++fj)
        b[fj] = *(const short8*)(Bs[buf] + (wn + fj * 16 + l16) * BK +
                                 ((((kk >> 3) + quad) ^ rmask) << 3));
#pragma unroll
      for (int fi = 0; fi < FI; ++fi)
#pragma unroll
        for (int fj = 0; fj < FJ; ++fj)
          acc[fi][fj] = __builtin_amdgcn_mfma_f32_16x16x32_bf16(
              a[fi], b[fj], acc[fi][fj], 0, 0, 0);
    }
  };

  if constexpr (DBUF) {
    stage(0, 0);
    __syncthreads();  // drain prologue loads
    int cur = 0;
    for (int k0 = 0; k0 < K; k0 += BK) {
      if (k0 + BK < K) stage(cur ^ 1, k0 + BK);  // prefetch next tile
      compute(cur);                               // overlaps with loads in flight
      __syncthreads();  // drain prefetch + guard buf reuse
      cur ^= 1;
    }
  } else {
    for (int k0 = 0; k0 < K; k0 += BK) {
      __syncthreads();
      stage(0, k0);
      __syncthreads();
      compute(0);
    }
  }

#pragma unroll
  for (int fi = 0; fi < FI; ++fi) {
#pragma unroll
    for (int fj = 0; fj < FJ; ++fj) {
      int col = n0 + wn + fj * 16 + l16;
      float bv = bias ? bias[col] : 0.0f;
#pragma unroll
      for (int r = 0; r < 4; ++r) {
        int row = m0 + wm + fi * 16 + quad * 4 + r;
        float val = acc[fi][fj][r] + bv;
        if (resid) val += ldres(resid + (size_t)row * N + col);
        if (GELU) val = gelu_new(val);
        if (VSPLIT && col < 1024) val *= 0.18033688011112042f;  // Q pre-scale
        if (VSPLIT && col >= 2048) {
          vTout[(size_t)(col - 2048) * 4096 + row] = f2bf(val);
        } else if constexpr (sizeof(TO) == 2) {
          C[(size_t)row * ldc + col] = f2bf(val);
        } else {
          C[(size_t)row * ldc + col] = val;
        }
      }
    }
  }
}

// ---------------- 256x256 GEMM, m201-style 8-phase interleave (T2+T3+T4+T5) ----------------
// 512 thr = 8 waves (2M x 4N), per-wave C = 128x64. LDS 128KB = [dbuf][half] x (128x64).
// Per K-tile: 4 phases {ds-read quadrant frags || stage 1 half-tile -> barrier ->
// 16 MFMA (setprio) -> barrier}, Z-ordered quadrants (12/4/8/4 ds_reads).
// Stage of a slot is always >= 1 phase after its last ds_read (race-free: the
// lgkm-wait before MFMA retires reads before barrier2; stages issue after it).
// vmcnt(2) only at phases 4/8 (2 loads = the current phase's half in flight);
// last iteration phase 4 drains with vmcnt(0). Stage plan per iter j
// (T1=2j+1,T2=2j+2,T3=2j+3): p1:T1.Ah1 p2:T1.Bh0 p3:T1.Bh1 p4:T2.Ah0 p5:T2.Ah1
// p6:T2.Bh0 p7:T2.Bh1 p8:T3.Ah0. Prologue: T0x4 + T1.Ah0, vmcnt(2).
template <bool GELU>
__global__ __launch_bounds__(512, 2) void gemm256(
    const u16* __restrict__ A, const u16* __restrict__ Bw,
    const float* __restrict__ bias, u16* __restrict__ C,
    int M, int N, int K, int lda, int ldc) {
  __shared__ __align__(16) u16 As[2][2][128 * 64];
  __shared__ __align__(16) u16 Bs[2][2][128 * 64];
  const int tid = threadIdx.x;
  const int w = tid >> 6, lane = tid & 63;
  const int quad = lane >> 4, l16 = lane & 15;
  const int rmask = l16 & 7;
  // XCD-chunked mapping: id%8 = XCD; XCDs tile 4x2 over (m,n); 32 locals = 4m x 8n
  const int id = blockIdx.x;
  const int xcd = id & 7, local = id >> 3;
  const int mt = (xcd & 3) * 4 + (local >> 3);
  const int nt = (xcd >> 2) * 8 + (local & 7);
  const int m0 = mt * 256, n0 = nt * 256;
  const int aHalf = w >> 2;        // this wave's A half (128 rows)
  const int bHalf = (w & 3) >> 1;  // this wave's B half
  const int bRow0 = (w & 1) * 64;  // row base within B half

  // staging: wave w owns chunks (w*2+i), i=0,1 of each 16KB half-tile.
  const int srow = lane >> 3, sq = lane & 7;
  int row_[2], ss_[2];
#pragma unroll
  for (int i = 0; i < 2; ++i) {
    row_[i] = (w * 2 + i) * 8 + srow;  // 0..127 within half
    ss_[i] = sq ^ (row_[i] & 7);       // source-side XOR seg swizzle
  }
  const u16* aSrc[2][2];  // [i][half]
  const u16* bSrc[2][2];
#pragma unroll
  for (int i = 0; i < 2; ++i)
#pragma unroll
    for (int hf = 0; hf < 2; ++hf) {
      aSrc[i][hf] = A + (size_t)(m0 + hf * 128 + row_[i]) * lda + ss_[i] * 8;
      bSrc[i][hf] = Bw + (size_t)(n0 + hf * 128 + row_[i]) * K + ss_[i] * 8;
    }

  const int ntk = K >> 6;   // 64-wide K-tiles (even; K%128==0)
  const int nIt = ntk >> 1;

  float4v acc[8][4] = {};
  short8 af[4][2], bf[2][2];

  auto dsA = [&](int buf, int mh) {
#pragma unroll
    for (int mi = 0; mi < 4; ++mi)
#pragma unroll
      for (int k2 = 0; k2 < 2; ++k2)
        af[mi][k2] = *(const short8*)(&As[buf][aHalf][(mh * 64 + mi * 16 + l16) * 64 +
                                                      (((k2 * 4 + quad) ^ rmask) << 3)]);
  };
  auto dsB = [&](int buf, int nh) {
#pragma unroll
    for (int nb = 0; nb < 2; ++nb)
#pragma unroll
      for (int k2 = 0; k2 < 2; ++k2)
        bf[nb][k2] = *(const short8*)(&Bs[buf][bHalf][(bRow0 + (nh * 2 + nb) * 16 + l16) * 64 +
                                                      (((k2 * 4 + quad) ^ rmask) << 3)]);
  };
  auto mfmaQ = [&](int mh, int nh) {
    __builtin_amdgcn_s_setprio(1);
#pragma unroll
    for (int mi = 0; mi < 4; ++mi)
#pragma unroll
      for (int nb = 0; nb < 2; ++nb)
#pragma unroll
        for (int k2 = 0; k2 < 2; ++k2)
          acc[mh * 4 + mi][nh * 2 + nb] = __builtin_amdgcn_mfma_f32_16x16x32_bf16(
              af[mi][k2], bf[nb][k2], acc[mh * 4 + mi][nh * 2 + nb], 0, 0, 0);
    __builtin_amdgcn_s_setprio(0);
  };
  auto stA = [&](int t, int hf) {
    if (t < ntk) {
#pragma unroll
      for (int i = 0; i < 2; ++i)
        gload_lds16(aSrc[i][hf] + t * 64, &As[t & 1][hf][(w * 2 + i) * 512]);
    }
  };
  auto stB = [&](int t, int hf) {
    if (t < ntk) {
#pragma unroll
      for (int i = 0; i < 2; ++i)
        gload_lds16(bSrc[i][hf] + t * 64, &Bs[t & 1][hf][(w * 2 + i) * 512]);
    }
  };
#define BAR() asm volatile("s_barrier" ::: "memory")

  // prologue: T0 all 4 halves + T1.Ah0; allow T1.Ah0 (2 loads) in flight
  stA(0, 0); stA(0, 1); stB(0, 0); stB(0, 1); stA(1, 0);
  asm volatile("s_waitcnt vmcnt(2)" ::: "memory");
  BAR();

  for (int j = 0; j < nIt; ++j) {
    const int T1 = 2 * j + 1, T2 = 2 * j + 2, T3 = 2 * j + 3;
    const bool last = (j == nIt - 1);
    // ---- K-tile 2j (buf 0): quadrants Z-order (m0n0, m0n1, m1n1, m1n0)
    dsA(0, 0); dsB(0, 0); stA(T1, 1); BAR(); mfmaQ(0, 0); BAR();
    dsB(0, 1);            stB(T1, 0); BAR(); mfmaQ(0, 1); BAR();
    dsA(0, 1);            stB(T1, 1); BAR(); mfmaQ(1, 1); BAR();
    dsB(0, 0);            stA(T2, 0);
    if (last) { asm volatile("s_waitcnt vmcnt(0)" ::: "memory"); }
    else      { asm volatile("s_waitcnt vmcnt(2)" ::: "memory"); }
    BAR(); mfmaQ(1, 0); BAR();
    // ---- K-tile 2j+1 (buf 1)
    dsA(1, 0); dsB(1, 0); stA(T2, 1); BAR(); mfmaQ(0, 0); BAR();
    dsB(1, 1);            stB(T2, 0); BAR(); mfmaQ(0, 1); BAR();
    dsA(1, 1);            stB(T2, 1); BAR(); mfmaQ(1, 1); BAR();
    dsB(1, 0);            stA(T3, 0);
    if (!last) { asm volatile("s_waitcnt vmcnt(2)" ::: "memory"); }
    BAR(); mfmaQ(1, 0); BAR();
  }
#undef BAR

#pragma unroll
  for (int mi = 0; mi < 8; ++mi) {
#pragma unroll
    for (int ni = 0; ni < 4; ++ni) {
      int col = n0 + (w & 3) * 64 + ni * 16 + l16;
      float bv = bias[col];
#pragma unroll
      for (int r = 0; r < 4; ++r) {
        int row = m0 + (w >> 2) * 128 + mi * 16 + quad * 4 + r;
        float val = acc[mi][ni][r] + bv;
        if (GELU) val = gelu_new(val);
        C[(size_t)row * ldc + col] = f2bf(val);
      }
    }
  }
}

// ---------------- single-pass flash attention (causal, online softmax, exp2) ----------------
__global__ __launch_bounds__(256) void attn_flash(u16* __restrict__ qk,
                                                  const u16* __restrict__ vT) {
  constexpr int PADK = 72;
  constexpr float THR2 = 10.0f;  // defer-max threshold, log2 domain (P <= 2^10)
  __shared__ __align__(16) u16 Ks[64 * PADK];
  __shared__ __align__(16) u16 Vt[64 * PADK];
  __shared__ __align__(16) u16 Ps[4][16 * PADK];
  const int id = blockIdx.x;
  const int qt = 31 - (id >> 5);  // longest blocks first
  const int combo = id & 31;
  const int head = combo >> 1, b = combo & 1;
  const int tid = threadIdx.x;
  const int w = tid >> 6, lane = tid & 63;
  const int quad = lane >> 4, l16 = lane & 15;
  const int q0 = qt * 64;
  const size_t tokB = (size_t)b * 2048;

  short8 aq[2];
#pragma unroll
  for (int ks = 0; ks < 2; ++ks)
    aq[ks] = *(const short8*)(qk + (tokB + q0 + w * 16 + l16) * 2048 +
                              head * 64 + ks * 32 + quad * 8);

  const u16* kbase = qk + tokB * 2048 + 1024 + head * 64;   // + (kk0+row)*2048 + seg*8
  const u16* vbase = vT + (size_t)head * 64 * 4096 + tokB;  // + row*4096 + kk0 + seg*8

  // ones-column B-fragment: col 0 of a 16-col tile = 1.0, rest 0.
  short8 bones = {};
  if (l16 == 0) {
#pragma unroll
    for (int j = 0; j < 8; ++j) bones[j] = (short)0x3F80;
  }

  float m_st[4] = {-1e30f, -1e30f, -1e30f, -1e30f};
  float4v o_acc[4] = {};
  float4v o5 = {0.f, 0.f, 0.f, 0.f};  // row-sums (col 0 lanes only)

  // staging geometry: each thread owns 2 consecutive 16B segs of one row
  const int srow = tid >> 2;
  const int sseg = (tid & 3) * 2;
  const u16* kptr = kbase + (size_t)srow * 2048 + sseg * 8;
  const u16* vptr = vbase + (size_t)srow * 4096 + sseg * 8;
  u16* ksl = Ks + srow * PADK + sseg * 8;
  u16* vsl = Vt + srow * PADK + sseg * 8;

  // prologue: prefetch tile 0 into regs
  short8 pk0 = *(const short8*)(kptr);
  short8 pk1 = *(const short8*)(kptr + 8);
  short8 pv0 = *(const short8*)(vptr);
  short8 pv1 = *(const short8*)(vptr + 8);

  for (int kt = 0; kt <= qt; ++kt) {
    const int kk0 = kt * 64;
    __syncthreads();  // previous compute done reading Ks/Vt
    *(short8*)(ksl) = pk0;
    *(short8*)(ksl + 8) = pk1;
    *(short8*)(vsl) = pv0;
    *(short8*)(vsl + 8) = pv1;
    __syncthreads();  // LDS writes visible
    if (kt < qt) {    // T14: issue next-tile loads; they fly during compute
      const u16* kp = kptr + (size_t)(kk0 + 64) * 2048;
      const u16* vp = vptr + kk0 + 64;
      pk0 = *(const short8*)(kp);
      pk1 = *(const short8*)(kp + 8);
      pv0 = *(const short8*)(vp);
      pv1 = *(const short8*)(vp + 8);
    }

    float4v s[4];
    __builtin_amdgcn_s_setprio(1);
#pragma unroll
    for (int fj = 0; fj < 4; ++fj) {
      float4v t = {0.f, 0.f, 0.f, 0.f};
#pragma unroll
      for (int ks = 0; ks < 2; ++ks) {
        short8 bk = *(const short8*)(Ks + (fj * 16 + l16) * PADK + ks * 32 + quad * 8);
        t = __builtin_amdgcn_mfma_f32_16x16x32_bf16(aq[ks], bk, t, 0, 0, 0);
      }
      s[fj] = t;
    }
    __builtin_amdgcn_s_setprio(0);
    if (kt == qt) {
#pragma unroll
      for (int fj = 0; fj < 4; ++fj) {
        int col = kk0 + fj * 16 + l16;
#pragma unroll
        for (int r = 0; r < 4; ++r) {
          int row = q0 + w * 16 + quad * 4 + r;
          if (col > row) s[fj][r] = -1e30f;
        }
      }
    }
    float mx[4];
#pragma unroll
    for (int r = 0; r < 4; ++r) {
      float m = fmaxf(fmaxf(s[0][r], s[1][r]), fmaxf(s[2][r], s[3][r]));
      m = fmaxf(m, __shfl_xor(m, 1));
      m = fmaxf(m, __shfl_xor(m, 2));
      m = fmaxf(m, __shfl_xor(m, 4));
      m = fmaxf(m, __shfl_xor(m, 8));
      mx[r] = m;
    }
    // defer-max: only rescale when the max grew by more than THR2
    bool need = false;
#pragma unroll
    for (int r = 0; r < 4; ++r) need |= (mx[r] > m_st[r] + THR2);
    if (__any(need)) {
#pragma unroll
      for (int r = 0; r < 4; ++r) {
        float mnew = fmaxf(m_st[r], mx[r]);
        float al = __builtin_amdgcn_exp2f(m_st[r] - mnew);
        m_st[r] = mnew;
        o5[r] *= al;
#pragma unroll
        for (int fj = 0; fj < 4; ++fj) o_acc[fj][r] *= al;
      }
    }
    // P = exp2(s - m), packed bf16 convert, store to Ps
#pragma unroll
    for (int fj = 0; fj < 4; ++fj) {
#pragma unroll
      for (int r = 0; r < 4; r += 2) {
        float e0 = __builtin_amdgcn_exp2f(s[fj][r] - m_st[r]);
        float e1 = __builtin_amdgcn_exp2f(s[fj][r + 1] - m_st[r + 1]);
        unsigned int pp = cvt_pk_bf16(e0, e1);
        Ps[w][(quad * 4 + r) * PADK + fj * 16 + l16] = (u16)pp;
        Ps[w][(quad * 4 + r + 1) * PADK + fj * 16 + l16] = (u16)(pp >> 16);
      }
    }
    short8 ap[2];
#pragma unroll
    for (int ks = 0; ks < 2; ++ks)
      ap[ks] = *(const short8*)(&Ps[w][l16 * PADK + ks * 32 + quad * 8]);
    __builtin_amdgcn_s_setprio(1);
#pragma unroll
    for (int fj = 0; fj < 4; ++fj)
#pragma unroll
      for (int ks = 0; ks < 2; ++ks) {
        short8 bv = *(const short8*)(Vt + (fj * 16 + l16) * PADK + ks * 32 + quad * 8);
        o_acc[fj] = __builtin_amdgcn_mfma_f32_16x16x32_bf16(ap[ks], bv, o_acc[fj], 0, 0, 0);
      }
#pragma unroll
    for (int ks = 0; ks < 2; ++ks)
      o5 = __builtin_amdgcn_mfma_f32_16x16x32_bf16(ap[ks], bones, o5, 0, 0, 0);
    __builtin_amdgcn_s_setprio(0);
  }
#pragma unroll
  for (int r = 0; r < 4; ++r) {
    float lsum = __shfl(o5[r], lane & 48);  // broadcast col-0 lane of the quad
    float inv = 1.0f / lsum;
    int row = q0 + w * 16 + quad * 4 + r;
#pragma unroll
    for (int fj = 0; fj < 4; ++fj)
      qk[(tokB + row) * 2048 + head * 64 + fj * 16 + l16] =
          f2bf(o_acc[fj][r] * inv);
  }
}

// ---------------- launcher ----------------
extern "C" void kernel_launch(void* const* d_in, const int* in_sizes, int n_in,
                              void* d_out, int out_size, void* d_ws, size_t ws_size,
                              hipStream_t stream) {
  const float* x = (const float*)d_in[0];
  const float* W_Q = (const float*)d_in[1];
  const float* W_K = (const float*)d_in[2];
  const float* W_V = (const float*)d_in[3];
  const float* W_O = (const float*)d_in[4];
  const float* b_Q = (const float*)d_in[5];
  const float* b_K = (const float*)d_in[6];
  const float* b_V = (const float*)d_in[7];
  const float* b_O = (const float*)d_in[8];
  const float* W_in = (const float*)d_in[9];
  const float* b_in = (const float*)d_in[10];
  const float* W_out = (const float*)d_in[11];
  const float* b_out = (const float*)d_in[12];
  float* out = (float*)d_out;

  char* ws = (char*)d_ws;
  u16* Wqkv = (u16*)(ws);                 // [0, 6291456)
  u16* Wot  = (u16*)(ws + 6291456);       // [6291456, 8388608)
  u16* Wib  = (u16*)(ws + 8388608);       // [8388608, 16777216)
  u16* Wob  = (u16*)(ws + 16777216);      // [16777216, 25165824)
  float* bqkv = (float*)(ws + 25165824);  // [25165824, 25178112)
  u16* xn   = (u16*)(ws + 25178112);      // [25178112, 33566720)
  u16* qk   = (u16*)(ws + 33566720);      // [33566720, 50343936)  4096*2048 bf16
  u16* vT   = (u16*)(ws + 50343936);      // [50343936, 58732544)  1024*4096 bf16
  u16* hbuf = (u16*)(ws + 33566720);      // overlays qk+vT, 4096*4096, ends 67121152
  float* rm = (float*)(ws + 67121152);    // [67121152, 83898368)

  cvt_bf16_multi<<<5632, 256, 0, stream>>>(W_Q, W_K, W_V, W_in, W_out,
                                           Wqkv, Wqkv + 1048576, Wqkv + 2097152,
                                           Wib, Wob);
  prep_wo<<<512, 256, 0, stream>>>(W_O, Wot);
  prep_bqkv<<<12, 256, 0, stream>>>(b_Q, b_K, b_V, bqkv);

  ln_f32<<<4096, 256, 0, stream>>>(x, xn);
  // QKV: Q,K -> qk[4096][2048] (Q pre-scaled); V -> vT[1024][4096]
  gemm_bt<128, 64, false, true, false, u16, float><<<dim3(32, 24), 256, 0, stream>>>(
      xn, Wqkv, bqkv, (const float*)nullptr, qk, vT, 4096, 3072, 1024, 1024, 2048);
  attn_flash<<<1024, 256, 0, stream>>>(qk, vT);
  // attn-out: BN=64/BK=64 + swizzle + prefetch dbuf (512 blocks = 2/CU).
  gemm_bt<64, 64, false, false, true, float, float><<<dim3(32, 16), 256, 0, stream>>>(
      qk /*z in q half, lda=2048*/, Wot, b_O, x, rm, nullptr, 4096, 1024, 1024, 2048, 1024);
  ln_f32<<<4096, 256, 0, stream>>>(rm, xn);
  // MLP-in: 256x256 8-phase pipeline (256 blocks = 1/CU, 8 waves).
  gemm256<true><<<256, 512, 0, stream>>>(xn, Wib, b_in, hbuf,
                                         4096, 4096, 1024, 1024, 4096);
  // MLP-out: BN=64/BK=64 + swizzle + prefetch dbuf (512 blocks = 2/CU).
  gemm_bt<64, 64, false, false, true, float, float><<<dim3(32, 16), 256, 0, stream>>>(
      hbuf, Wob, b_out, rm, out, nullptr, 4096, 1024, 4096, 4096, 1024);
}